// Round 7
// baseline (98.305 us; speedup 1.0000x reference)
//
#include <hip/hip_runtime.h>
#include <stdint.h>

#define IN_C 64
#define HH 256
#define WW 256
#define HW (HH * WW)
#define OUT_C 128
#define OH 254
#define OW 254
#define OHW (OH * OW)

#define XR 6     // staged input rows (4 out rows + 2 halo)
#define XW 66    // staged input width (64 + 2 halo)
#define CPAD 72  // channel stride in shorts: 144 B -> b128 B-frag reads bank-balanced

typedef __attribute__((ext_vector_type(4))) float f32x4;
typedef __attribute__((ext_vector_type(8))) __bf16 bf16x8;

__device__ __forceinline__ unsigned short f2bf(float f) {
  union { float f; unsigned u; } v; v.f = f;
  unsigned r = v.u + 0x7FFFu + ((v.u >> 16) & 1u);  // RNE (inputs finite/normal)
  return (unsigned short)(r >> 16);
}

// Weights -> A-fragment order bf16:
// wt[tap][ch][mt][lane][j] = bf16( W[o=mt*16+(lane&15)][c=ch*32+(lane>>4)*8+j][tap] )
__global__ void prep_w(const float* __restrict__ w, unsigned short* __restrict__ wt) {
  const int idx = blockIdx.x * 256 + threadIdx.x;
  if (idx >= 9 * 8192) return;
  const int j    = idx & 7;
  const int lane = (idx >> 3) & 63;
  const int mt   = (idx >> 9) & 7;
  const int ch   = (idx >> 12) & 1;
  const int tap  = idx >> 13;
  const int o = mt * 16 + (lane & 15);
  const int c = ch * 32 + (lane >> 4) * 8 + j;
  wt[idx] = f2bf(w[(o * IN_C + c) * 9 + tap]);
}

// 512-thread block: 4 out rows x 64 px x 128 ch. 8 waves = (row 0..3, mhalf 0..1).
// Two-phase staging: rows 0-3 -> barrier -> (rows 4-5 write + ky=0 compute) -> barrier
// -> ky=1,2.  A-frags: distance-2 prefetch through 3 statically-rotated reg buffers.
__global__ __launch_bounds__(512, 2) void conv_mfma(
    const float* __restrict__ x, const unsigned short* __restrict__ wt,
    const float* __restrict__ bias, float* __restrict__ out) {
  __shared__ __align__(16) unsigned short Xs[XR * XW * CPAD];  // 57024 B

  const int tid  = threadIdx.x;
  const int wave = tid >> 6;
  const int lane = tid & 63;
  const int x0 = blockIdx.x * 64;   // 0,64,128,192 (mask stores at xc >= 254)
  const int y0 = blockIdx.y * 4;    // 0..252 (mask stores at y >= 254)

  const int mhalf = wave & 1;   // half of the 128 out-channels
  const int row   = wave >> 1;  // which of the 4 output rows
  const int nlane = lane & 15;
  const int quad  = lane >> 4;

  // A-frag base; chunks 0 and 1 prefetched before staging (in flight throughout)
  const bf16x8* __restrict__ Wp = ((const bf16x8*)wt) + lane + (mhalf * 4) * 64;
  bf16x8 af[3][4];
#pragma unroll
  for (int mt = 0; mt < 4; ++mt) af[0][mt] = Wp[(0 * 8 + mt) * 64];
#pragma unroll
  for (int mt = 0; mt < 4; ++mt) af[1][mt] = Wp[(1 * 8 + mt) * 64];

  // ---- staging thread mapping: (cq 0..15, xh 0..15, z 0..1)
  const int cq = tid & 15;          // channels cq*4 .. cq*4+3
  const int xh = (tid >> 4) & 15;   // xx = xh*4 .. xh*4+3
  const int z  = tid >> 8;          // 0..1

  // phase 1: rows 0..3 (2 per thread)
#pragma unroll
  for (int k = 0; k < 2; ++k) {
    const int r = z * 2 + k;
    const int yr = (y0 + r > 255) ? 255 : (y0 + r);
    const float* bx = x + yr * WW + x0 + xh * 4;
    f32x4 vv[4];
#pragma unroll
    for (int cc = 0; cc < 4; ++cc) vv[cc] = *(const f32x4*)(bx + (cq * 4 + cc) * HW);
#pragma unroll
    for (int xxi = 0; xxi < 4; ++xxi) {
      unsigned u0 = (unsigned)f2bf(vv[0][xxi]) | ((unsigned)f2bf(vv[1][xxi]) << 16);
      unsigned u1 = (unsigned)f2bf(vv[2][xxi]) | ((unsigned)f2bf(vv[3][xxi]) << 16);
      *(uint2*)&Xs[(r * XW + xh * 4 + xxi) * CPAD + cq * 4] = make_uint2(u0, u1);
    }
  }
  // halo xx=64,65 for rows 0..3 (8 px-rows x 64 ch = 512 writes, one per thread)
  {
    const int c = tid & 63;
    const int q = tid >> 6;             // 0..7
    const int xxt = 64 + (q & 1);
    const int r = q >> 1;               // 0..3
    const int yr = (y0 + r > 255) ? 255 : (y0 + r);
    int xg = x0 + xxt;
    if (xg > WW - 1) xg = WW - 1;
    Xs[(r * XW + xxt) * CPAD + c] = f2bf(x[c * HW + yr * WW + xg]);
  }

  // issue global loads for rows 4,5 NOW (1 row per thread, z picks the row);
  // they drain while phase-1 finishes and across barrier 1
  f32x4 vv2[4];
  float hv2;
  {
    const int r = 4 + z;
    const int yr = (y0 + r > 255) ? 255 : (y0 + r);
    const float* bx = x + yr * WW + x0 + xh * 4;
#pragma unroll
    for (int cc = 0; cc < 4; ++cc) vv2[cc] = *(const f32x4*)(bx + (cq * 4 + cc) * HW);
    // halo rows 4,5: 4 px-rows x 64 ch = 256 loads (tid < 256)
    const int c = tid & 63;
    const int q = (tid >> 6) & 3;
    const int xxt = 64 + (q & 1);
    const int rh = 4 + (q >> 1);
    const int yrh = (y0 + rh > 255) ? 255 : (y0 + rh);
    int xg = x0 + xxt;
    if (xg > WW - 1) xg = WW - 1;
    hv2 = x[c * HW + yrh * WW + xg];
  }

  // accumulators init with bias (C/D row = quad*4+reg = out-ch)
  f32x4 acc[4][4];
#pragma unroll
  for (int mt = 0; mt < 4; ++mt) {
    const f32x4 bv = *(const f32x4*)(bias + (mhalf * 4 + mt) * 16 + quad * 4);
#pragma unroll
    for (int nt = 0; nt < 4; ++nt) acc[mt][nt] = bv;
  }

  __syncthreads();  // barrier 1: rows 0-3 ready

  // write rows 4,5 (+halo) to LDS — readers wait at barrier 2
  {
    const int r = 4 + z;
#pragma unroll
    for (int xxi = 0; xxi < 4; ++xxi) {
      unsigned u0 = (unsigned)f2bf(vv2[0][xxi]) | ((unsigned)f2bf(vv2[1][xxi]) << 16);
      unsigned u1 = (unsigned)f2bf(vv2[2][xxi]) | ((unsigned)f2bf(vv2[3][xxi]) << 16);
      *(uint2*)&Xs[(r * XW + xh * 4 + xxi) * CPAD + cq * 4] = make_uint2(u0, u1);
    }
    if (tid < 256) {
      const int c = tid & 63;
      const int q = (tid >> 6) & 3;
      const int xxt = 64 + (q & 1);
      const int rh = 4 + (q >> 1);
      Xs[(rh * XW + xxt) * CPAD + c] = f2bf(hv2);
    }
  }

  // ---- chunk machinery (all indices compile-time via full unroll)
#define PF(c)                                                                  \
  if ((c) < 18) {                                                              \
    _Pragma("unroll")                                                          \
    for (int mt = 0; mt < 4; ++mt) af[(c) % 3][mt] = Wp[((c) * 8 + mt) * 64];  \
  }
#define COMP(c)                                                                \
  {                                                                            \
    const int tap = (c) >> 1, ky = tap / 3, kx = tap - ky * 3;                 \
    const unsigned short* xrow = &Xs[((row + ky) * XW + kx) * CPAD +           \
                                     quad * 8 + ((c) & 1) * 32];               \
    bf16x8 bfr[4];                                                             \
    _Pragma("unroll")                                                          \
    for (int nt = 0; nt < 4; ++nt)                                             \
      bfr[nt] = *(const bf16x8*)&xrow[(nt * 16 + nlane) * CPAD];               \
    _Pragma("unroll")                                                          \
    for (int mt = 0; mt < 4; ++mt)                                             \
      _Pragma("unroll")                                                        \
      for (int nt = 0; nt < 4; ++nt)                                           \
        acc[mt][nt] = __builtin_amdgcn_mfma_f32_16x16x32_bf16(                 \
            af[(c) % 3][mt], bfr[nt], acc[mt][nt], 0, 0, 0);                   \
  }

  // ky = 0 : chunks 0..5 (need staged rows 0..3 only) — overlaps rows-4/5 staging
#pragma unroll
  for (int c = 0; c < 6; ++c) { PF(c + 2); COMP(c); }

  __syncthreads();  // barrier 2: rows 4,5 ready

  // ky = 1,2 : chunks 6..17
#pragma unroll
  for (int c = 6; c < 18; ++c) { PF(c + 2); COMP(c); }

#undef PF
#undef COMP

  // ---- epilogue: C/D col = lane&15 (pixel), row = quad*4+reg (out-ch)
  const int y = y0 + row;
  if (y < OH) {
#pragma unroll
    for (int mt = 0; mt < 4; ++mt) {
      const int obase = (mhalf * 4 + mt) * 16 + quad * 4;
#pragma unroll
      for (int nt = 0; nt < 4; ++nt) {
        const int xc = x0 + nt * 16 + nlane;
        if (xc < OW) {
          float* dst = out + obase * OHW + y * OW + xc;
#pragma unroll
          for (int reg = 0; reg < 4; ++reg)
            dst[reg * OHW] = acc[mt][nt][reg];
        }
      }
    }
  }
}

extern "C" void kernel_launch(void* const* d_in, const int* in_sizes, int n_in,
                              void* d_out, int out_size, void* d_ws, size_t ws_size,
                              hipStream_t stream) {
  const float* x = (const float*)d_in[0];
  const float* w = (const float*)d_in[1];
  const float* b = (const float*)d_in[2];
  float* out = (float*)d_out;
  unsigned short* wt = (unsigned short*)d_ws;  // 147456 B fragment-ordered bf16 weights

  prep_w<<<dim3(288), dim3(256), 0, stream>>>(w, wt);
  conv_mfma<<<dim3(4, 64), dim3(512), 0, stream>>>(x, wt, b, out);
}